// Round 2
// baseline (116.813 us; speedup 1.0000x reference)
//
#include <hip/hip_runtime.h>
#include <math.h>

#define HW 28
#define PP 784           // 28*28
#define PR 30            // padded rows (-1..28)
#define PC 32            // padded cols stride (-1..28 at idx 0..29, +2 spare)

// ---------------- K1: 1x1 adder conv 256->64 ----------------
// grid (7, 4, 8), block 256. Thread: 8 contiguous px, 1 co. w staged in LDS.
__global__ __launch_bounds__(256) void k1_adder1x1(const float* __restrict__ x,
                                                   const float* __restrict__ w1,
                                                   float* __restrict__ h1) {
    __shared__ float ws[16][257];
    const int n      = blockIdx.z;
    const int cobase = blockIdx.y * 16;
    const int pxg    = threadIdx.x & 15;
    const int co_l   = threadIdx.x >> 4;
    const int px0    = blockIdx.x * 128 + pxg * 8;

    #pragma unroll
    for (int c = 0; c < 16; ++c)
        ws[c][threadIdx.x] = w1[(size_t)(cobase + c) * 256 + threadIdx.x];
    __syncthreads();

    if (px0 >= PP) return;

    float a0 = 0.f, a1 = 0.f, a2 = 0.f, a3 = 0.f;
    float a4 = 0.f, a5 = 0.f, a6 = 0.f, a7 = 0.f;
    const float* xp = x + (size_t)n * 256 * PP + px0;
    #pragma unroll 4
    for (int ci = 0; ci < 256; ++ci) {
        float4 u = *(const float4*)(xp + (size_t)ci * PP);
        float4 v = *(const float4*)(xp + (size_t)ci * PP + 4);
        float  w = ws[co_l][ci];
        a0 += fabsf(u.x - w); a1 += fabsf(u.y - w);
        a2 += fabsf(u.z - w); a3 += fabsf(u.w - w);
        a4 += fabsf(v.x - w); a5 += fabsf(v.y - w);
        a6 += fabsf(v.z - w); a7 += fabsf(v.w - w);
    }
    float* op = h1 + ((size_t)n * 64 + cobase + co_l) * PP + px0;
    *(float4*)(op)     = make_float4(-a0, -a1, -a2, -a3);
    *(float4*)(op + 4) = make_float4(-a4, -a5, -a6, -a7);
}

// ---------------- K2: depthwise 3x3 adder (PEG) + BN1 + ReLU -> PADDED layout ----------------
// one thread per padded cell (incl. halo cells, written as 0). grid 1920, block 256.
__global__ __launch_bounds__(256) void k2_peg_bn_relu(const float* __restrict__ h1,
                                                      const float* __restrict__ wp,
                                                      const float* __restrict__ g1,
                                                      const float* __restrict__ b1,
                                                      const float* __restrict__ m1,
                                                      const float* __restrict__ v1,
                                                      float* __restrict__ h2p) {
    int o = blockIdx.x * 256 + threadIdx.x;     // < 8*64*30*32
    int col = o & 31;
    int t   = o >> 5;
    int r   = t % PR;  t /= PR;
    int c   = t & 63;
    int n   = t >> 6;

    float val = 0.f;
    if (col >= 1 && col <= HW && r >= 1 && r <= HW) {
        const int xx = col - 1, y = r - 1;
        const float* base = h1 + ((size_t)(n * 64 + c)) * PP;
        const float* wc   = wp + c * 9;
        float acc = 0.f;
        #pragma unroll
        for (int kh = 0; kh < 3; ++kh) {
            int yy = y + kh - 1;
            bool rv = (yy >= 0) & (yy < HW);
            #pragma unroll
            for (int kw = 0; kw < 3; ++kw) {
                int xc = xx + kw - 1;
                float v = (rv && xc >= 0 && xc < HW) ? base[yy * HW + xc] : 0.f;
                acc += fabsf(v - wc[kh * 3 + kw]);
            }
        }
        float inv = g1[c] * rsqrtf(v1[c] + 1e-5f);
        float bb  = b1[c] - m1[c] * inv;
        val = fmaxf(-acc * inv + bb, 0.f);
    }
    h2p[o] = val;
}

// ---------------- K3: 3x3 adder conv 64->64 (pad 1) + BN2 + ReLU ----------------
// grid (28 y, 4 cog, 8 n), block 128. Thread: 4 contiguous px, 1 co.
// Input is pre-padded (h2p): no predication, aligned vector loads, 1 cacheline/(ci,kh).
__global__ __launch_bounds__(128) void k3_adder3x3_bn_relu(const float* __restrict__ h2p,
                                                           const float* __restrict__ w2,
                                                           const float* __restrict__ g2,
                                                           const float* __restrict__ b2,
                                                           const float* __restrict__ m2,
                                                           const float* __restrict__ v2,
                                                           float* __restrict__ h3r) {
    __shared__ float ws[16][577];  // [co_l][ci*9+tap]
    const int y      = blockIdx.x;        // 0..27 output row
    const int cobase = blockIdx.y * 16;
    const int n      = blockIdx.z;
    const int co_l   = threadIdx.x & 15;
    const int grp    = threadIdx.x >> 4;  // 0..7 (7 active)

    #pragma unroll
    for (int c = 0; c < 16; ++c)
        for (int r = threadIdx.x; r < 576; r += 128)
            ws[c][r] = w2[(size_t)(cobase + c) * 576 + r];
    __syncthreads();

    if (grp >= 7) return;
    const int px0 = grp * 4;
    const int co  = cobase + co_l;

    float acc0 = 0.f, acc1 = 0.f, acc2 = 0.f, acc3 = 0.f;
    // output row y needs input rows y-1..y+1 == padded rows y..y+2
    const float* nbase = h2p + ((size_t)(n * 64) * PR + y) * PC + px0;
    #pragma unroll 2
    for (int ci = 0; ci < 64; ++ci) {
        const float* rp = nbase + (size_t)ci * (PR * PC);
        const float* wr = &ws[co_l][ci * 9];
        #pragma unroll
        for (int kh = 0; kh < 3; ++kh) {
            float4 a = *(const float4*)(rp + kh * PC);
            float2 b = *(const float2*)(rp + kh * PC + 4);
            float w0 = wr[kh * 3 + 0], w1 = wr[kh * 3 + 1], w2v = wr[kh * 3 + 2];
            acc0 += fabsf(a.x - w0) + fabsf(a.y - w1) + fabsf(a.z - w2v);
            acc1 += fabsf(a.y - w0) + fabsf(a.z - w1) + fabsf(a.w - w2v);
            acc2 += fabsf(a.z - w0) + fabsf(a.w - w1) + fabsf(b.x - w2v);
            acc3 += fabsf(a.w - w0) + fabsf(b.x - w1) + fabsf(b.y - w2v);
        }
    }
    float inv = g2[co] * rsqrtf(v2[co] + 1e-5f);
    float bb  = b2[co] - m2[co] * inv;
    float4 o;
    o.x = fmaxf(-acc0 * inv + bb, 0.f);
    o.y = fmaxf(-acc1 * inv + bb, 0.f);
    o.z = fmaxf(-acc2 * inv + bb, 0.f);
    o.w = fmaxf(-acc3 * inv + bb, 0.f);
    *(float4*)(h3r + ((size_t)n * 64 + co) * PP + y * HW + px0) = o;
}

// ---------------- K6: 1x1 adder conv 64->256 + BN3 + residual + ReLU ----------------
// grid (7, 16, 8), block 256. Thread: 8 contiguous px, 1 co.
__global__ __launch_bounds__(256) void k6_adder1x1_bn_res_relu(const float* __restrict__ h3r,
                                                               const float* __restrict__ w3,
                                                               const float* __restrict__ x,
                                                               const float* __restrict__ g3,
                                                               const float* __restrict__ b3,
                                                               const float* __restrict__ m3,
                                                               const float* __restrict__ v3,
                                                               float* __restrict__ out) {
    __shared__ float ws[16][65];
    const int n      = blockIdx.z;
    const int cobase = blockIdx.y * 16;
    const int pxg    = threadIdx.x & 15;
    const int co_l   = threadIdx.x >> 4;
    const int px0    = blockIdx.x * 128 + pxg * 8;

    #pragma unroll
    for (int k = 0; k < 4; ++k) {
        int idx = k * 256 + threadIdx.x;
        int c = idx >> 6, r = idx & 63;
        ws[c][r] = w3[(size_t)cobase * 64 + idx];
    }
    __syncthreads();

    if (px0 >= PP) return;

    float a0 = 0.f, a1 = 0.f, a2 = 0.f, a3 = 0.f;
    float a4 = 0.f, a5 = 0.f, a6 = 0.f, a7 = 0.f;
    const float* hp = h3r + (size_t)n * 64 * PP + px0;
    #pragma unroll 4
    for (int ci = 0; ci < 64; ++ci) {
        float4 u = *(const float4*)(hp + (size_t)ci * PP);
        float4 v = *(const float4*)(hp + (size_t)ci * PP + 4);
        float  w = ws[co_l][ci];
        a0 += fabsf(u.x - w); a1 += fabsf(u.y - w);
        a2 += fabsf(u.z - w); a3 += fabsf(u.w - w);
        a4 += fabsf(v.x - w); a5 += fabsf(v.y - w);
        a6 += fabsf(v.z - w); a7 += fabsf(v.w - w);
    }
    const int co = cobase + co_l;
    float inv = g3[co] * rsqrtf(v3[co] + 1e-5f);
    float bb  = b3[co] - m3[co] * inv;
    size_t obase = ((size_t)n * 256 + co) * PP + px0;
    float4 r0 = *(const float4*)(x + obase);
    float4 r1 = *(const float4*)(x + obase + 4);
    float4 o0, o1;
    o0.x = fmaxf(-a0 * inv + bb + r0.x, 0.f);
    o0.y = fmaxf(-a1 * inv + bb + r0.y, 0.f);
    o0.z = fmaxf(-a2 * inv + bb + r0.z, 0.f);
    o0.w = fmaxf(-a3 * inv + bb + r0.w, 0.f);
    o1.x = fmaxf(-a4 * inv + bb + r1.x, 0.f);
    o1.y = fmaxf(-a5 * inv + bb + r1.y, 0.f);
    o1.z = fmaxf(-a6 * inv + bb + r1.z, 0.f);
    o1.w = fmaxf(-a7 * inv + bb + r1.w, 0.f);
    *(float4*)(out + obase)     = o0;
    *(float4*)(out + obase + 4) = o1;
}

extern "C" void kernel_launch(void* const* d_in, const int* in_sizes, int n_in,
                              void* d_out, int out_size, void* d_ws, size_t ws_size,
                              hipStream_t stream) {
    const float* x  = (const float*)d_in[0];
    const float* w1 = (const float*)d_in[1];
    const float* wp = (const float*)d_in[2];
    const float* w2 = (const float*)d_in[3];
    const float* w3 = (const float*)d_in[4];
    const float* g1 = (const float*)d_in[5];
    const float* b1 = (const float*)d_in[6];
    const float* m1 = (const float*)d_in[7];
    const float* v1 = (const float*)d_in[8];
    const float* g2 = (const float*)d_in[9];
    const float* b2 = (const float*)d_in[10];
    const float* m2 = (const float*)d_in[11];
    const float* v2 = (const float*)d_in[12];
    const float* g3 = (const float*)d_in[13];
    const float* b3 = (const float*)d_in[14];
    const float* m3 = (const float*)d_in[15];
    const float* v3 = (const float*)d_in[16];
    float* out = (float*)d_out;

    // ws layout (bytes): h1 @0 (1605632), h2p @1605632 (1966080), h3r @0 (reuses h1; h1 dead after K2)
    float* h1  = (float*)d_ws;                      // 8*64*784 floats
    float* h2p = (float*)((char*)d_ws + 1605632);   // 8*64*30*32 floats, padded
    float* h3r = h1;                                // alias: safe, stream-ordered

    k1_adder1x1<<<dim3(7, 4, 8), 256, 0, stream>>>(x, w1, h1);
    k2_peg_bn_relu<<<dim3(1920), 256, 0, stream>>>(h1, wp, g1, b1, m1, v1, h2p);
    k3_adder3x3_bn_relu<<<dim3(28, 4, 8), 128, 0, stream>>>(h2p, w2, g2, b2, m2, v2, h3r);
    k6_adder1x1_bn_res_relu<<<dim3(7, 16, 8), 256, 0, stream>>>(h3r, w3, x, g3, b3, m3, v3, out);
}

// Round 3
// 99.507 us; speedup vs baseline: 1.1739x; 1.1739x over previous
//
#include <hip/hip_runtime.h>
#include <math.h>

#define HW 28
#define PP 784           // 28*28
#define PR 30            // padded rows (-1..28)
#define PC 32            // padded cols stride

// ---------------- K1: 1x1 adder conv 256->64 ----------------
// block 512 = (8 pxg x 16 co x 2 cic). Thread: 4 px, 1 co, 128 ci. LDS partial reduce.
__global__ __launch_bounds__(512) void k1_adder1x1(const float* __restrict__ x,
                                                   const float* __restrict__ w1,
                                                   float* __restrict__ h1) {
    __shared__ float ws[16][260];        // stride 260: 16B-aligned rows, 2-way banks max
    __shared__ float pl[2 * 8 * 16 * 4]; // [cic][pxg][co][4px]
    const int tid    = threadIdx.x;
    const int n      = blockIdx.z;
    const int cobase = blockIdx.y * 16;
    const int co_l   = tid & 15;
    const int pxg    = (tid >> 4) & 7;
    const int cic    = tid >> 7;         // 0..1
    const int px0    = blockIdx.x * 32 + pxg * 4;

    for (int r = tid; r < 4096; r += 512) {
        int c = r >> 8, ci = r & 255;
        ws[c][ci] = w1[(size_t)(cobase + c) * 256 + ci];
    }
    __syncthreads();

    float a0 = 0.f, a1 = 0.f, a2 = 0.f, a3 = 0.f;
    if (px0 < PP) {
        const float* xp = x + ((size_t)n * 256 + cic * 128) * PP + px0;
        const float* wp = &ws[co_l][cic * 128];
        #pragma unroll 4
        for (int i = 0; i < 128; i += 4) {
            float4 wv = *(const float4*)(wp + i);
            float4 u0 = *(const float4*)(xp + (size_t)(i + 0) * PP);
            float4 u1 = *(const float4*)(xp + (size_t)(i + 1) * PP);
            float4 u2 = *(const float4*)(xp + (size_t)(i + 2) * PP);
            float4 u3 = *(const float4*)(xp + (size_t)(i + 3) * PP);
            a0 += fabsf(u0.x - wv.x); a1 += fabsf(u0.y - wv.x);
            a2 += fabsf(u0.z - wv.x); a3 += fabsf(u0.w - wv.x);
            a0 += fabsf(u1.x - wv.y); a1 += fabsf(u1.y - wv.y);
            a2 += fabsf(u1.z - wv.y); a3 += fabsf(u1.w - wv.y);
            a0 += fabsf(u2.x - wv.z); a1 += fabsf(u2.y - wv.z);
            a2 += fabsf(u2.z - wv.z); a3 += fabsf(u2.w - wv.z);
            a0 += fabsf(u3.x - wv.w); a1 += fabsf(u3.y - wv.w);
            a2 += fabsf(u3.z - wv.w); a3 += fabsf(u3.w - wv.w);
        }
    }
    float4* pl4 = (float4*)pl;
    pl4[(cic * 8 + pxg) * 16 + co_l] = make_float4(a0, a1, a2, a3);
    __syncthreads();

    if (cic == 0 && px0 < PP) {
        float4 s0 = pl4[(0 * 8 + pxg) * 16 + co_l];
        float4 s1 = pl4[(1 * 8 + pxg) * 16 + co_l];
        float4 o = make_float4(-(s0.x + s1.x), -(s0.y + s1.y),
                               -(s0.z + s1.z), -(s0.w + s1.w));
        *(float4*)(h1 + ((size_t)n * 64 + cobase + co_l) * PP + px0) = o;
    }
}

// ---------------- K2: depthwise 3x3 adder (PEG) + BN1 + ReLU -> PADDED layout ----------------
__global__ __launch_bounds__(256) void k2_peg_bn_relu(const float* __restrict__ h1,
                                                      const float* __restrict__ wp,
                                                      const float* __restrict__ g1,
                                                      const float* __restrict__ b1,
                                                      const float* __restrict__ m1,
                                                      const float* __restrict__ v1,
                                                      float* __restrict__ h2p) {
    int o = blockIdx.x * 256 + threadIdx.x;     // < 8*64*30*32
    int col = o & 31;
    int t   = o >> 5;
    int r   = t % PR;  t /= PR;
    int c   = t & 63;
    int n   = t >> 6;

    float val = 0.f;
    if (col >= 1 && col <= HW && r >= 1 && r <= HW) {
        const int xx = col - 1, y = r - 1;
        const float* base = h1 + ((size_t)(n * 64 + c)) * PP;
        const float* wc   = wp + c * 9;
        float acc = 0.f;
        #pragma unroll
        for (int kh = 0; kh < 3; ++kh) {
            int yy = y + kh - 1;
            bool rv = (yy >= 0) & (yy < HW);
            #pragma unroll
            for (int kw = 0; kw < 3; ++kw) {
                int xc = xx + kw - 1;
                float v = (rv && xc >= 0 && xc < HW) ? base[yy * HW + xc] : 0.f;
                acc += fabsf(v - wc[kh * 3 + kw]);
            }
        }
        float inv = g1[c] * rsqrtf(v1[c] + 1e-5f);
        float bb  = b1[c] - m1[c] * inv;
        val = fmaxf(-acc * inv + bb, 0.f);
    }
    h2p[o] = val;
}

// ---------------- K3: 3x3 adder conv 64->64 (pad 1) + BN2 + ReLU ----------------
// block 448 = (7 pxg x 16 co x 4 cic). Thread: 4 px, 1 co, 16 ci. LDS partial reduce.
__global__ __launch_bounds__(448) void k3_adder3x3_bn_relu(const float* __restrict__ h2p,
                                                           const float* __restrict__ w2,
                                                           const float* __restrict__ g2,
                                                           const float* __restrict__ b2,
                                                           const float* __restrict__ m2,
                                                           const float* __restrict__ v2,
                                                           float* __restrict__ h3r) {
    __shared__ float ws[4][16][145];     // [cic][co][ci_l*9+tap]
    __shared__ float pl[4 * 7 * 16 * 4]; // [cic][pxg][co][4px]
    const int tid    = threadIdx.x;
    const int y      = blockIdx.x;       // output row 0..27
    const int cobase = blockIdx.y * 16;
    const int n      = blockIdx.z;
    const int co_l   = tid & 15;
    const int pxg    = (tid >> 4) % 7;
    const int cic    = tid / 112;        // 0..3
    const int px0    = pxg * 4;

    for (int r = tid; r < 9216; r += 448) {
        int co = r / 576, rem = r % 576;
        int ci = rem / 9, t = rem % 9;
        ws[ci >> 4][co][(ci & 15) * 9 + t] = w2[(size_t)(cobase + co) * 576 + rem];
    }
    __syncthreads();

    float a0 = 0.f, a1 = 0.f, a2 = 0.f, a3 = 0.f;
    {
        const float* nb = h2p + (((size_t)(n * 64 + cic * 16)) * PR + y) * PC + px0;
        const float* wb = ws[cic][co_l];
        #pragma unroll 2
        for (int i = 0; i < 16; ++i) {
            const float* rp = nb + (size_t)i * (PR * PC);
            const float* wr = wb + i * 9;
            #pragma unroll
            for (int kh = 0; kh < 3; ++kh) {
                float4 a = *(const float4*)(rp + kh * PC);
                float2 b = *(const float2*)(rp + kh * PC + 4);
                float w0 = wr[kh * 3 + 0], w1v = wr[kh * 3 + 1], w2v = wr[kh * 3 + 2];
                a0 += fabsf(a.x - w0) + fabsf(a.y - w1v) + fabsf(a.z - w2v);
                a1 += fabsf(a.y - w0) + fabsf(a.z - w1v) + fabsf(a.w - w2v);
                a2 += fabsf(a.z - w0) + fabsf(a.w - w1v) + fabsf(b.x - w2v);
                a3 += fabsf(a.w - w0) + fabsf(b.x - w1v) + fabsf(b.y - w2v);
            }
        }
    }
    float4* pl4 = (float4*)pl;
    pl4[(cic * 7 + pxg) * 16 + co_l] = make_float4(a0, a1, a2, a3);
    __syncthreads();

    if (cic == 0) {
        float4 s0 = pl4[(0 * 7 + pxg) * 16 + co_l];
        float4 s1 = pl4[(1 * 7 + pxg) * 16 + co_l];
        float4 s2 = pl4[(2 * 7 + pxg) * 16 + co_l];
        float4 s3 = pl4[(3 * 7 + pxg) * 16 + co_l];
        const int co = cobase + co_l;
        float inv = g2[co] * rsqrtf(v2[co] + 1e-5f);
        float bb  = b2[co] - m2[co] * inv;
        float4 o;
        o.x = fmaxf(-(s0.x + s1.x + s2.x + s3.x) * inv + bb, 0.f);
        o.y = fmaxf(-(s0.y + s1.y + s2.y + s3.y) * inv + bb, 0.f);
        o.z = fmaxf(-(s0.z + s1.z + s2.z + s3.z) * inv + bb, 0.f);
        o.w = fmaxf(-(s0.w + s1.w + s2.w + s3.w) * inv + bb, 0.f);
        *(float4*)(h3r + ((size_t)n * 64 + co) * PP + y * HW + px0) = o;
    }
}

// ---------------- K6: 1x1 adder conv 64->256 + BN3 + residual + ReLU ----------------
// block 256 = (16 pxg x 16 co). Thread: 4 px, 1 co, 64 ci. grid (13,16,8)=1664 blocks.
__global__ __launch_bounds__(256) void k6_adder1x1_bn_res_relu(const float* __restrict__ h3r,
                                                               const float* __restrict__ w3,
                                                               const float* __restrict__ x,
                                                               const float* __restrict__ g3,
                                                               const float* __restrict__ b3,
                                                               const float* __restrict__ m3,
                                                               const float* __restrict__ v3,
                                                               float* __restrict__ out) {
    __shared__ float ws[16][68];         // stride 68: 16B-aligned rows
    const int tid    = threadIdx.x;
    const int n      = blockIdx.z;
    const int cobase = blockIdx.y * 16;
    const int co_l   = tid & 15;
    const int pxg    = tid >> 4;
    const int px0    = blockIdx.x * 64 + pxg * 4;

    for (int r = tid; r < 1024; r += 256) {
        int c = r >> 6, ci = r & 63;
        ws[c][ci] = w3[(size_t)(cobase + c) * 64 + ci];
    }
    __syncthreads();

    if (px0 >= PP) return;

    float a0 = 0.f, a1 = 0.f, a2 = 0.f, a3 = 0.f;
    const float* hp = h3r + (size_t)n * 64 * PP + px0;
    #pragma unroll 4
    for (int i = 0; i < 64; i += 4) {
        float4 wv = *(const float4*)(&ws[co_l][i]);
        float4 u0 = *(const float4*)(hp + (size_t)(i + 0) * PP);
        float4 u1 = *(const float4*)(hp + (size_t)(i + 1) * PP);
        float4 u2 = *(const float4*)(hp + (size_t)(i + 2) * PP);
        float4 u3 = *(const float4*)(hp + (size_t)(i + 3) * PP);
        a0 += fabsf(u0.x - wv.x); a1 += fabsf(u0.y - wv.x);
        a2 += fabsf(u0.z - wv.x); a3 += fabsf(u0.w - wv.x);
        a0 += fabsf(u1.x - wv.y); a1 += fabsf(u1.y - wv.y);
        a2 += fabsf(u1.z - wv.y); a3 += fabsf(u1.w - wv.y);
        a0 += fabsf(u2.x - wv.z); a1 += fabsf(u2.y - wv.z);
        a2 += fabsf(u2.z - wv.z); a3 += fabsf(u2.w - wv.z);
        a0 += fabsf(u3.x - wv.w); a1 += fabsf(u3.y - wv.w);
        a2 += fabsf(u3.z - wv.w); a3 += fabsf(u3.w - wv.w);
    }
    const int co = cobase + co_l;
    float inv = g3[co] * rsqrtf(v3[co] + 1e-5f);
    float bb  = b3[co] - m3[co] * inv;
    size_t obase = ((size_t)n * 256 + co) * PP + px0;
    float4 res = *(const float4*)(x + obase);
    float4 o;
    o.x = fmaxf(-a0 * inv + bb + res.x, 0.f);
    o.y = fmaxf(-a1 * inv + bb + res.y, 0.f);
    o.z = fmaxf(-a2 * inv + bb + res.z, 0.f);
    o.w = fmaxf(-a3 * inv + bb + res.w, 0.f);
    *(float4*)(out + obase) = o;
}

extern "C" void kernel_launch(void* const* d_in, const int* in_sizes, int n_in,
                              void* d_out, int out_size, void* d_ws, size_t ws_size,
                              hipStream_t stream) {
    const float* x  = (const float*)d_in[0];
    const float* w1 = (const float*)d_in[1];
    const float* wp = (const float*)d_in[2];
    const float* w2 = (const float*)d_in[3];
    const float* w3 = (const float*)d_in[4];
    const float* g1 = (const float*)d_in[5];
    const float* b1 = (const float*)d_in[6];
    const float* m1 = (const float*)d_in[7];
    const float* v1 = (const float*)d_in[8];
    const float* g2 = (const float*)d_in[9];
    const float* b2 = (const float*)d_in[10];
    const float* m2 = (const float*)d_in[11];
    const float* v2 = (const float*)d_in[12];
    const float* g3 = (const float*)d_in[13];
    const float* b3 = (const float*)d_in[14];
    const float* m3 = (const float*)d_in[15];
    const float* v3 = (const float*)d_in[16];
    float* out = (float*)d_out;

    float* h1  = (float*)d_ws;                      // 8*64*784 floats
    float* h2p = (float*)((char*)d_ws + 1605632);   // 8*64*30*32 floats, padded
    float* h3r = h1;                                // alias: h1 dead after K2

    k1_adder1x1<<<dim3(25, 4, 8), 512, 0, stream>>>(x, w1, h1);
    k2_peg_bn_relu<<<dim3(1920), 256, 0, stream>>>(h1, wp, g1, b1, m1, v1, h2p);
    k3_adder3x3_bn_relu<<<dim3(28, 4, 8), 448, 0, stream>>>(h2p, w2, g2, b2, m2, v2, h3r);
    k6_adder1x1_bn_res_relu<<<dim3(13, 16, 8), 256, 0, stream>>>(h3r, w3, x, g3, b3, m3, v3, out);
}

// Round 4
// 67.865 us; speedup vs baseline: 1.7213x; 1.4663x over previous
//
#include <hip/hip_runtime.h>
#include <math.h>

#define HW 28
#define PR 30            // padded rows
#define PC 32            // padded col stride; col 0 = x[-1], col k+1 = x[k], col 29 = x[28]
#define PPAD (PR * PC)   // 960 floats per padded plane

// 4px x 3kw taps for one co: s = {a.x,a.y,a.z,a.w,b.x,b.y} is the 6-wide window
__device__ __forceinline__ void tap3(const float4 a, const float2 b,
                                     const float w0, const float w1, const float w2,
                                     float4& acc) {
    acc.x += fabsf(a.x - w0) + fabsf(a.y - w1) + fabsf(a.z - w2);
    acc.y += fabsf(a.y - w0) + fabsf(a.z - w1) + fabsf(a.w - w2);
    acc.z += fabsf(a.z - w0) + fabsf(a.w - w1) + fabsf(b.x - w2);
    acc.w += fabsf(a.w - w0) + fabsf(b.x - w1) + fabsf(b.y - w2);
}

// ---------------- K1: 1x1 adder 256->64, out = PADDED h1p ----------------
// grid (112, 4), block 448 = 4 cog x 14 pxg x 8 cic. Thread: 4px x 4co x 32ci.
__global__ __launch_bounds__(448) void k1_adder1x1(const float* __restrict__ x,
                                                   const float* __restrict__ w1,
                                                   float* __restrict__ h1p) {
    __shared__ float  ws[256 * 20];   // [ci][16co + 4 pad]
    __shared__ float4 pl[1792];       // [cic8][pxg14][cog4][j4]
    const int tid    = threadIdx.x;
    const int cog    = tid & 3;
    const int pxg    = (tid >> 2) % 14;
    const int cic    = tid / 56;                 // 0..7
    const int n      = blockIdx.x / 14;
    const int p0     = (blockIdx.x % 14) * 56 + pxg * 4;   // 0..780
    const int cobase = blockIdx.y * 16;

    for (int idx = tid; idx < 16 * 256; idx += 448) {
        int co = idx >> 8, ci = idx & 255;
        ws[ci * 20 + co] = w1[(size_t)(cobase + co) * 256 + ci];
    }
    __syncthreads();

    float4 acc0 = {0,0,0,0}, acc1 = acc0, acc2 = acc0, acc3 = acc0;
    const float* xp = x + ((size_t)n * 256 + cic * 32) * 784 + p0;
    const float* wp = ws + cic * 32 * 20 + cog * 4;
    #pragma unroll 4
    for (int i = 0; i < 32; ++i) {
        float4 u = *(const float4*)(xp + (size_t)i * 784);
        float4 w = *(const float4*)(wp + i * 20);
        acc0.x += fabsf(u.x - w.x); acc0.y += fabsf(u.y - w.x); acc0.z += fabsf(u.z - w.x); acc0.w += fabsf(u.w - w.x);
        acc1.x += fabsf(u.x - w.y); acc1.y += fabsf(u.y - w.y); acc1.z += fabsf(u.z - w.y); acc1.w += fabsf(u.w - w.y);
        acc2.x += fabsf(u.x - w.z); acc2.y += fabsf(u.y - w.z); acc2.z += fabsf(u.z - w.z); acc2.w += fabsf(u.w - w.z);
        acc3.x += fabsf(u.x - w.w); acc3.y += fabsf(u.y - w.w); acc3.z += fabsf(u.z - w.w); acc3.w += fabsf(u.w - w.w);
    }
    const int pbase = pxg * 16 + cog * 4;
    pl[cic * 224 + pbase + 0] = acc0;
    pl[cic * 224 + pbase + 1] = acc1;
    pl[cic * 224 + pbase + 2] = acc2;
    pl[cic * 224 + pbase + 3] = acc3;
    __syncthreads();

    if (tid < 224) {
        const int j = cic;   // 0..3
        float4 s = pl[pbase + j];
        #pragma unroll
        for (int c = 1; c < 8; ++c) {
            float4 t = pl[c * 224 + pbase + j];
            s.x += t.x; s.y += t.y; s.z += t.z; s.w += t.w;
        }
        const int co = cobase + cog * 4 + j;
        const int y = p0 / 28, xx = p0 % 28;
        float* op = h1p + ((size_t)(n * 64 + co) * PR + y + 1) * PC + xx + 1;
        op[0] = -s.x; op[1] = -s.y; op[2] = -s.z; op[3] = -s.w;
    }
}

// ---------------- K2: depthwise 3x3 (PEG) + BN1 + ReLU, padded->padded ----------------
// grid 392, block 256. Thread: 4 px of one (n,c) row. No predication.
__global__ __launch_bounds__(256) void k2_peg_bn_relu(const float* __restrict__ h1p,
                                                      const float* __restrict__ wp,
                                                      const float* __restrict__ g1,
                                                      const float* __restrict__ b1,
                                                      const float* __restrict__ m1,
                                                      const float* __restrict__ v1,
                                                      float* __restrict__ h2p) {
    const int t   = blockIdx.x * 256 + threadIdx.x;   // < 8*64*196
    const int pxq = t % 196;
    const int c   = (t / 196) & 63;
    const int n   = t / (196 * 64);
    const int p0  = pxq * 4;
    const int y   = p0 / 28, xx = p0 % 28;

    const float* base = h1p + ((size_t)(n * 64 + c) * PR + y) * PC + xx;
    const float* wc   = wp + c * 9;
    float4 acc = {0,0,0,0};
    #pragma unroll
    for (int kh = 0; kh < 3; ++kh) {
        float4 a = *(const float4*)(base + kh * PC);
        float2 b = *(const float2*)(base + kh * PC + 4);
        tap3(a, b, wc[kh * 3 + 0], wc[kh * 3 + 1], wc[kh * 3 + 2], acc);
    }
    float inv = g1[c] * rsqrtf(v1[c] + 1e-5f);
    float bb  = b1[c] - m1[c] * inv;
    float* op = h2p + ((size_t)(n * 64 + c) * PR + y + 1) * PC + xx + 1;
    op[0] = fmaxf(-acc.x * inv + bb, 0.f);
    op[1] = fmaxf(-acc.y * inv + bb, 0.f);
    op[2] = fmaxf(-acc.z * inv + bb, 0.f);
    op[3] = fmaxf(-acc.w * inv + bb, 0.f);
}

// ---------------- K3: 3x3 adder 64->64 + BN2 + ReLU ----------------
// grid (14, 4, 8), block 448 = 4 cog x 14 pxg(2 rows x 7) x 8 cic. Thread: 4px x 4co x 8ci x 9taps.
__global__ __launch_bounds__(448) void k3_adder3x3_bn_relu(const float* __restrict__ h2p,
                                                           const float* __restrict__ w2,
                                                           const float* __restrict__ g2,
                                                           const float* __restrict__ b2,
                                                           const float* __restrict__ m2,
                                                           const float* __restrict__ v2,
                                                           float* __restrict__ h3) {
    __shared__ float  ws[576 * 20];   // [ci*9+tap][16co + 4 pad]
    __shared__ float4 pl[1792];       // [cic8][pxg14][cog4][j4]
    const int tid    = threadIdx.x;
    const int cog    = tid & 3;
    const int pxg    = (tid >> 2) % 14;
    const int cic    = tid / 56;                  // 0..7
    const int y0     = blockIdx.x * 2;
    const int cobase = blockIdx.y * 16;
    const int n      = blockIdx.z;
    const int yl     = pxg / 7;                   // 0..1
    const int xx0    = (pxg % 7) * 4;             // 0..24
    const int Y      = y0 + yl;                   // output row

    for (int idx = tid; idx < 9216; idx += 448) {
        int co = idx / 576;                        // const-div
        int rem = idx - co * 576;                  // ci*9 + tap
        ws[rem * 20 + co] = w2[(size_t)(cobase + co) * 576 + rem];
    }
    __syncthreads();

    float4 acc0 = {0,0,0,0}, acc1 = acc0, acc2 = acc0, acc3 = acc0;
    #pragma unroll 2
    for (int i = 0; i < 8; ++i) {
        const float* rp = h2p + ((size_t)(n * 64 + cic * 8 + i) * PR + Y) * PC + xx0;
        const float* wb = ws + (cic * 8 + i) * 180 + cog * 4;
        #pragma unroll
        for (int kh = 0; kh < 3; ++kh) {
            float4 a = *(const float4*)(rp + kh * PC);
            float2 b = *(const float2*)(rp + kh * PC + 4);
            const float* wk = wb + kh * 60;
            float4 w0 = *(const float4*)(wk);
            float4 w1v = *(const float4*)(wk + 20);
            float4 w2v = *(const float4*)(wk + 40);
            tap3(a, b, w0.x, w1v.x, w2v.x, acc0);
            tap3(a, b, w0.y, w1v.y, w2v.y, acc1);
            tap3(a, b, w0.z, w1v.z, w2v.z, acc2);
            tap3(a, b, w0.w, w1v.w, w2v.w, acc3);
        }
    }
    const int pbase = pxg * 16 + cog * 4;
    pl[cic * 224 + pbase + 0] = acc0;
    pl[cic * 224 + pbase + 1] = acc1;
    pl[cic * 224 + pbase + 2] = acc2;
    pl[cic * 224 + pbase + 3] = acc3;
    __syncthreads();

    if (tid < 224) {
        const int j = cic;
        float4 s = pl[pbase + j];
        #pragma unroll
        for (int c = 1; c < 8; ++c) {
            float4 t = pl[c * 224 + pbase + j];
            s.x += t.x; s.y += t.y; s.z += t.z; s.w += t.w;
        }
        const int co = cobase + cog * 4 + j;
        float inv = g2[co] * rsqrtf(v2[co] + 1e-5f);
        float bb  = b2[co] - m2[co] * inv;
        float4 o;
        o.x = fmaxf(-s.x * inv + bb, 0.f);
        o.y = fmaxf(-s.y * inv + bb, 0.f);
        o.z = fmaxf(-s.z * inv + bb, 0.f);
        o.w = fmaxf(-s.w * inv + bb, 0.f);
        *(float4*)(h3 + (size_t)(n * 64 + co) * 784 + Y * 28 + xx0) = o;
    }
}

// ---------------- K6: 1x1 adder 64->256 + BN3 + residual + ReLU ----------------
// grid (112, 8), block 448 = 8 cog x 14 pxg x 4 cic. Thread: 4px x 4co x 16ci.
__global__ __launch_bounds__(448) void k6_adder1x1_bn_res_relu(const float* __restrict__ h3,
                                                               const float* __restrict__ w3,
                                                               const float* __restrict__ x,
                                                               const float* __restrict__ g3,
                                                               const float* __restrict__ b3,
                                                               const float* __restrict__ m3,
                                                               const float* __restrict__ v3,
                                                               float* __restrict__ out) {
    __shared__ float  ws[64 * 36];    // [ci][32co + 4 pad]
    __shared__ float4 pl[1792];       // [cic4][pxg14][cog8][j4]
    const int tid    = threadIdx.x;
    const int cog    = tid & 7;
    const int pxg    = (tid >> 3) % 14;
    const int cic    = tid / 112;                 // 0..3
    const int n      = blockIdx.x / 14;
    const int p0     = (blockIdx.x % 14) * 56 + pxg * 4;
    const int cobase = blockIdx.y * 32;

    for (int idx = tid; idx < 2048; idx += 448) {
        int co = idx >> 6, ci = idx & 63;
        ws[ci * 36 + co] = w3[(size_t)(cobase + co) * 64 + ci];
    }
    __syncthreads();

    float4 acc0 = {0,0,0,0}, acc1 = acc0, acc2 = acc0, acc3 = acc0;
    const float* hp = h3 + ((size_t)n * 64 + cic * 16) * 784 + p0;
    const float* wp = ws + cic * 16 * 36 + cog * 4;
    #pragma unroll 4
    for (int i = 0; i < 16; ++i) {
        float4 u = *(const float4*)(hp + (size_t)i * 784);
        float4 w = *(const float4*)(wp + i * 36);
        acc0.x += fabsf(u.x - w.x); acc0.y += fabsf(u.y - w.x); acc0.z += fabsf(u.z - w.x); acc0.w += fabsf(u.w - w.x);
        acc1.x += fabsf(u.x - w.y); acc1.y += fabsf(u.y - w.y); acc1.z += fabsf(u.z - w.y); acc1.w += fabsf(u.w - w.y);
        acc2.x += fabsf(u.x - w.z); acc2.y += fabsf(u.y - w.z); acc2.z += fabsf(u.z - w.z); acc2.w += fabsf(u.w - w.z);
        acc3.x += fabsf(u.x - w.w); acc3.y += fabsf(u.y - w.w); acc3.z += fabsf(u.z - w.w); acc3.w += fabsf(u.w - w.w);
    }
    const int pbase = pxg * 32 + cog * 4;
    pl[cic * 448 + pbase + 0] = acc0;
    pl[cic * 448 + pbase + 1] = acc1;
    pl[cic * 448 + pbase + 2] = acc2;
    pl[cic * 448 + pbase + 3] = acc3;
    __syncthreads();

    {   // all 448 threads finalize: j = cic
        const int j = cic;
        float4 s = pl[pbase + j];
        #pragma unroll
        for (int c = 1; c < 4; ++c) {
            float4 t = pl[c * 448 + pbase + j];
            s.x += t.x; s.y += t.y; s.z += t.z; s.w += t.w;
        }
        const int co = cobase + cog * 4 + j;
        float inv = g3[co] * rsqrtf(v3[co] + 1e-5f);
        float bb  = b3[co] - m3[co] * inv;
        size_t obase = ((size_t)n * 256 + co) * 784 + p0;
        float4 r = *(const float4*)(x + obase);
        float4 o;
        o.x = fmaxf(-s.x * inv + bb + r.x, 0.f);
        o.y = fmaxf(-s.y * inv + bb + r.y, 0.f);
        o.z = fmaxf(-s.z * inv + bb + r.z, 0.f);
        o.w = fmaxf(-s.w * inv + bb + r.w, 0.f);
        *(float4*)(out + obase) = o;
    }
}

extern "C" void kernel_launch(void* const* d_in, const int* in_sizes, int n_in,
                              void* d_out, int out_size, void* d_ws, size_t ws_size,
                              hipStream_t stream) {
    const float* x  = (const float*)d_in[0];
    const float* w1 = (const float*)d_in[1];
    const float* wp = (const float*)d_in[2];
    const float* w2 = (const float*)d_in[3];
    const float* w3 = (const float*)d_in[4];
    const float* g1 = (const float*)d_in[5];
    const float* b1 = (const float*)d_in[6];
    const float* m1 = (const float*)d_in[7];
    const float* v1 = (const float*)d_in[8];
    const float* g2 = (const float*)d_in[9];
    const float* b2 = (const float*)d_in[10];
    const float* m2 = (const float*)d_in[11];
    const float* v2 = (const float*)d_in[12];
    const float* g3 = (const float*)d_in[13];
    const float* b3 = (const float*)d_in[14];
    const float* m3 = (const float*)d_in[15];
    const float* v3 = (const float*)d_in[16];
    float* out = (float*)d_out;

    // ws: h1p [8*64*960] @0, h2p [8*64*960] @491520, h3 [8*64*784] @983040 (floats)
    float* h1p = (float*)d_ws;
    float* h2p = h1p + 491520;
    float* h3  = h2p + 491520;

    // zero both padded buffers (halo must be 0 each call; graph-capturable, stream-ordered)
    hipMemsetAsync(d_ws, 0, 2u * 491520u * 4u, stream);

    k1_adder1x1<<<dim3(112, 4), 448, 0, stream>>>(x, w1, h1p);
    k2_peg_bn_relu<<<dim3(392), 256, 0, stream>>>(h1p, wp, g1, b1, m1, v1, h2p);
    k3_adder3x3_bn_relu<<<dim3(14, 4, 8), 448, 0, stream>>>(h2p, w2, g2, b2, m2, v2, h3);
    k6_adder1x1_bn_res_relu<<<dim3(112, 8), 448, 0, stream>>>(h3, w3, x, g3, b3, m3, v3, out);
}

// Round 5
// 67.333 us; speedup vs baseline: 1.7349x; 1.0079x over previous
//
#include <hip/hip_runtime.h>
#include <math.h>

#define HW 28
#define PR 30            // padded rows
#define PC 32            // padded col stride; col 0 = x[-1], col k+1 = x[k], col 29 = x[28]
#define PPAD (PR * PC)   // 960 floats per padded plane

// 4px x 3kw taps for one co: s = {a.x,a.y,a.z,a.w,b.x,b.y} is the 6-wide window
__device__ __forceinline__ void tap3(const float4 a, const float2 b,
                                     const float w0, const float w1, const float w2,
                                     float4& acc) {
    acc.x += fabsf(a.x - w0) + fabsf(a.y - w1) + fabsf(a.z - w2);
    acc.y += fabsf(a.y - w0) + fabsf(a.z - w1) + fabsf(a.w - w2);
    acc.z += fabsf(a.z - w0) + fabsf(a.w - w1) + fabsf(b.x - w2);
    acc.w += fabsf(a.w - w0) + fabsf(b.x - w1) + fabsf(b.y - w2);
}

// ---------------- K0: zero h1p + h2p (rocclr fill is 40us for small sizes!) ----------------
// 960 blocks x 256 threads x 16B = 3,932,160 B exactly.
__global__ __launch_bounds__(256) void k0_zero(float4* __restrict__ p) {
    p[blockIdx.x * 256 + threadIdx.x] = make_float4(0.f, 0.f, 0.f, 0.f);
}

// ---------------- K1: 1x1 adder 256->64, out = PADDED h1p ----------------
// grid (112, 4), block 448 = 4 cog x 14 pxg x 8 cic. Thread: 4px x 4co x 32ci.
__global__ __launch_bounds__(448) void k1_adder1x1(const float* __restrict__ x,
                                                   const float* __restrict__ w1,
                                                   float* __restrict__ h1p) {
    __shared__ float  ws[256 * 20];   // [ci][16co + 4 pad]
    __shared__ float4 pl[1792];       // [cic8][pxg14][cog4][j4]
    const int tid    = threadIdx.x;
    const int cog    = tid & 3;
    const int pxg    = (tid >> 2) % 14;
    const int cic    = tid / 56;                 // 0..7
    const int n      = blockIdx.x / 14;
    const int p0     = (blockIdx.x % 14) * 56 + pxg * 4;   // 0..780
    const int cobase = blockIdx.y * 16;

    for (int idx = tid; idx < 16 * 256; idx += 448) {
        int co = idx >> 8, ci = idx & 255;
        ws[ci * 20 + co] = w1[(size_t)(cobase + co) * 256 + ci];
    }
    __syncthreads();

    float4 acc0 = {0,0,0,0}, acc1 = acc0, acc2 = acc0, acc3 = acc0;
    const float* xp = x + ((size_t)n * 256 + cic * 32) * 784 + p0;
    const float* wp = ws + cic * 32 * 20 + cog * 4;
    #pragma unroll 4
    for (int i = 0; i < 32; ++i) {
        float4 u = *(const float4*)(xp + (size_t)i * 784);
        float4 w = *(const float4*)(wp + i * 20);
        acc0.x += fabsf(u.x - w.x); acc0.y += fabsf(u.y - w.x); acc0.z += fabsf(u.z - w.x); acc0.w += fabsf(u.w - w.x);
        acc1.x += fabsf(u.x - w.y); acc1.y += fabsf(u.y - w.y); acc1.z += fabsf(u.z - w.y); acc1.w += fabsf(u.w - w.y);
        acc2.x += fabsf(u.x - w.z); acc2.y += fabsf(u.y - w.z); acc2.z += fabsf(u.z - w.z); acc2.w += fabsf(u.w - w.z);
        acc3.x += fabsf(u.x - w.w); acc3.y += fabsf(u.y - w.w); acc3.z += fabsf(u.z - w.w); acc3.w += fabsf(u.w - w.w);
    }
    const int pbase = pxg * 16 + cog * 4;
    pl[cic * 224 + pbase + 0] = acc0;
    pl[cic * 224 + pbase + 1] = acc1;
    pl[cic * 224 + pbase + 2] = acc2;
    pl[cic * 224 + pbase + 3] = acc3;
    __syncthreads();

    if (tid < 224) {
        const int j = cic;   // 0..3
        float4 s = pl[pbase + j];
        #pragma unroll
        for (int c = 1; c < 8; ++c) {
            float4 t = pl[c * 224 + pbase + j];
            s.x += t.x; s.y += t.y; s.z += t.z; s.w += t.w;
        }
        const int co = cobase + cog * 4 + j;
        const int y = p0 / 28, xx = p0 % 28;
        float* op = h1p + ((size_t)(n * 64 + co) * PR + y + 1) * PC + xx + 1;
        op[0] = -s.x; op[1] = -s.y; op[2] = -s.z; op[3] = -s.w;
    }
}

// ---------------- K2: depthwise 3x3 (PEG) + BN1 + ReLU, padded->padded ----------------
// grid 392, block 256. Thread: 4 px of one (n,c) row. No predication.
__global__ __launch_bounds__(256) void k2_peg_bn_relu(const float* __restrict__ h1p,
                                                      const float* __restrict__ wp,
                                                      const float* __restrict__ g1,
                                                      const float* __restrict__ b1,
                                                      const float* __restrict__ m1,
                                                      const float* __restrict__ v1,
                                                      float* __restrict__ h2p) {
    const int t   = blockIdx.x * 256 + threadIdx.x;   // < 8*64*196
    const int pxq = t % 196;
    const int c   = (t / 196) & 63;
    const int n   = t / (196 * 64);
    const int p0  = pxq * 4;
    const int y   = p0 / 28, xx = p0 % 28;

    const float* base = h1p + ((size_t)(n * 64 + c) * PR + y) * PC + xx;
    const float* wc   = wp + c * 9;
    float4 acc = {0,0,0,0};
    #pragma unroll
    for (int kh = 0; kh < 3; ++kh) {
        float4 a = *(const float4*)(base + kh * PC);
        float2 b = *(const float2*)(base + kh * PC + 4);
        tap3(a, b, wc[kh * 3 + 0], wc[kh * 3 + 1], wc[kh * 3 + 2], acc);
    }
    float inv = g1[c] * rsqrtf(v1[c] + 1e-5f);
    float bb  = b1[c] - m1[c] * inv;
    float* op = h2p + ((size_t)(n * 64 + c) * PR + y + 1) * PC + xx + 1;
    op[0] = fmaxf(-acc.x * inv + bb, 0.f);
    op[1] = fmaxf(-acc.y * inv + bb, 0.f);
    op[2] = fmaxf(-acc.z * inv + bb, 0.f);
    op[3] = fmaxf(-acc.w * inv + bb, 0.f);
}

// ---------------- K3: 3x3 adder 64->64 + BN2 + ReLU ----------------
// grid (14, 4, 8), block 448 = 4 cog x 14 pxg(2 rows x 7) x 8 cic. Thread: 4px x 4co x 8ci x 9taps.
__global__ __launch_bounds__(448) void k3_adder3x3_bn_relu(const float* __restrict__ h2p,
                                                           const float* __restrict__ w2,
                                                           const float* __restrict__ g2,
                                                           const float* __restrict__ b2,
                                                           const float* __restrict__ m2,
                                                           const float* __restrict__ v2,
                                                           float* __restrict__ h3) {
    __shared__ float  ws[576 * 20];   // [ci*9+tap][16co + 4 pad]
    __shared__ float4 pl[1792];       // [cic8][pxg14][cog4][j4]
    const int tid    = threadIdx.x;
    const int cog    = tid & 3;
    const int pxg    = (tid >> 2) % 14;
    const int cic    = tid / 56;                  // 0..7
    const int y0     = blockIdx.x * 2;
    const int cobase = blockIdx.y * 16;
    const int n      = blockIdx.z;
    const int yl     = pxg / 7;                   // 0..1
    const int xx0    = (pxg % 7) * 4;             // 0..24
    const int Y      = y0 + yl;                   // output row

    for (int idx = tid; idx < 9216; idx += 448) {
        int co = idx / 576;                        // const-div
        int rem = idx - co * 576;                  // ci*9 + tap
        ws[rem * 20 + co] = w2[(size_t)(cobase + co) * 576 + rem];
    }
    __syncthreads();

    float4 acc0 = {0,0,0,0}, acc1 = acc0, acc2 = acc0, acc3 = acc0;
    #pragma unroll 2
    for (int i = 0; i < 8; ++i) {
        const float* rp = h2p + ((size_t)(n * 64 + cic * 8 + i) * PR + Y) * PC + xx0;
        const float* wb = ws + (cic * 8 + i) * 180 + cog * 4;
        #pragma unroll
        for (int kh = 0; kh < 3; ++kh) {
            float4 a = *(const float4*)(rp + kh * PC);
            float2 b = *(const float2*)(rp + kh * PC + 4);
            const float* wk = wb + kh * 60;
            float4 w0 = *(const float4*)(wk);
            float4 w1v = *(const float4*)(wk + 20);
            float4 w2v = *(const float4*)(wk + 40);
            tap3(a, b, w0.x, w1v.x, w2v.x, acc0);
            tap3(a, b, w0.y, w1v.y, w2v.y, acc1);
            tap3(a, b, w0.z, w1v.z, w2v.z, acc2);
            tap3(a, b, w0.w, w1v.w, w2v.w, acc3);
        }
    }
    const int pbase = pxg * 16 + cog * 4;
    pl[cic * 224 + pbase + 0] = acc0;
    pl[cic * 224 + pbase + 1] = acc1;
    pl[cic * 224 + pbase + 2] = acc2;
    pl[cic * 224 + pbase + 3] = acc3;
    __syncthreads();

    if (tid < 224) {
        const int j = cic;
        float4 s = pl[pbase + j];
        #pragma unroll
        for (int c = 1; c < 8; ++c) {
            float4 t = pl[c * 224 + pbase + j];
            s.x += t.x; s.y += t.y; s.z += t.z; s.w += t.w;
        }
        const int co = cobase + cog * 4 + j;
        float inv = g2[co] * rsqrtf(v2[co] + 1e-5f);
        float bb  = b2[co] - m2[co] * inv;
        float4 o;
        o.x = fmaxf(-s.x * inv + bb, 0.f);
        o.y = fmaxf(-s.y * inv + bb, 0.f);
        o.z = fmaxf(-s.z * inv + bb, 0.f);
        o.w = fmaxf(-s.w * inv + bb, 0.f);
        *(float4*)(h3 + (size_t)(n * 64 + co) * 784 + Y * 28 + xx0) = o;
    }
}

// ---------------- K6: 1x1 adder 64->256 + BN3 + residual + ReLU ----------------
// grid (112, 8), block 448 = 8 cog x 14 pxg x 4 cic. Thread: 4px x 4co x 16ci.
__global__ __launch_bounds__(448) void k6_adder1x1_bn_res_relu(const float* __restrict__ h3,
                                                               const float* __restrict__ w3,
                                                               const float* __restrict__ x,
                                                               const float* __restrict__ g3,
                                                               const float* __restrict__ b3,
                                                               const float* __restrict__ m3,
                                                               const float* __restrict__ v3,
                                                               float* __restrict__ out) {
    __shared__ float  ws[64 * 36];    // [ci][32co + 4 pad]
    __shared__ float4 pl[1792];       // [cic4][pxg14][cog8][j4]
    const int tid    = threadIdx.x;
    const int cog    = tid & 7;
    const int pxg    = (tid >> 3) % 14;
    const int cic    = tid / 112;                 // 0..3
    const int n      = blockIdx.x / 14;
    const int p0     = (blockIdx.x % 14) * 56 + pxg * 4;
    const int cobase = blockIdx.y * 32;

    for (int idx = tid; idx < 2048; idx += 448) {
        int co = idx >> 6, ci = idx & 63;
        ws[ci * 36 + co] = w3[(size_t)(cobase + co) * 64 + ci];
    }
    __syncthreads();

    float4 acc0 = {0,0,0,0}, acc1 = acc0, acc2 = acc0, acc3 = acc0;
    const float* hp = h3 + ((size_t)n * 64 + cic * 16) * 784 + p0;
    const float* wp = ws + cic * 16 * 36 + cog * 4;
    #pragma unroll 4
    for (int i = 0; i < 16; ++i) {
        float4 u = *(const float4*)(hp + (size_t)i * 784);
        float4 w = *(const float4*)(wp + i * 36);
        acc0.x += fabsf(u.x - w.x); acc0.y += fabsf(u.y - w.x); acc0.z += fabsf(u.z - w.x); acc0.w += fabsf(u.w - w.x);
        acc1.x += fabsf(u.x - w.y); acc1.y += fabsf(u.y - w.y); acc1.z += fabsf(u.z - w.y); acc1.w += fabsf(u.w - w.y);
        acc2.x += fabsf(u.x - w.z); acc2.y += fabsf(u.y - w.z); acc2.z += fabsf(u.z - w.z); acc2.w += fabsf(u.w - w.z);
        acc3.x += fabsf(u.x - w.w); acc3.y += fabsf(u.y - w.w); acc3.z += fabsf(u.z - w.w); acc3.w += fabsf(u.w - w.w);
    }
    const int pbase = pxg * 32 + cog * 4;
    pl[cic * 448 + pbase + 0] = acc0;
    pl[cic * 448 + pbase + 1] = acc1;
    pl[cic * 448 + pbase + 2] = acc2;
    pl[cic * 448 + pbase + 3] = acc3;
    __syncthreads();

    {   // all 448 threads finalize: j = cic
        const int j = cic;
        float4 s = pl[pbase + j];
        #pragma unroll
        for (int c = 1; c < 4; ++c) {
            float4 t = pl[c * 448 + pbase + j];
            s.x += t.x; s.y += t.y; s.z += t.z; s.w += t.w;
        }
        const int co = cobase + cog * 4 + j;
        float inv = g3[co] * rsqrtf(v3[co] + 1e-5f);
        float bb  = b3[co] - m3[co] * inv;
        size_t obase = ((size_t)n * 256 + co) * 784 + p0;
        float4 r = *(const float4*)(x + obase);
        float4 o;
        o.x = fmaxf(-s.x * inv + bb + r.x, 0.f);
        o.y = fmaxf(-s.y * inv + bb + r.y, 0.f);
        o.z = fmaxf(-s.z * inv + bb + r.z, 0.f);
        o.w = fmaxf(-s.w * inv + bb + r.w, 0.f);
        *(float4*)(out + obase) = o;
    }
}

extern "C" void kernel_launch(void* const* d_in, const int* in_sizes, int n_in,
                              void* d_out, int out_size, void* d_ws, size_t ws_size,
                              hipStream_t stream) {
    const float* x  = (const float*)d_in[0];
    const float* w1 = (const float*)d_in[1];
    const float* wp = (const float*)d_in[2];
    const float* w2 = (const float*)d_in[3];
    const float* w3 = (const float*)d_in[4];
    const float* g1 = (const float*)d_in[5];
    const float* b1 = (const float*)d_in[6];
    const float* m1 = (const float*)d_in[7];
    const float* v1 = (const float*)d_in[8];
    const float* g2 = (const float*)d_in[9];
    const float* b2 = (const float*)d_in[10];
    const float* m2 = (const float*)d_in[11];
    const float* v2 = (const float*)d_in[12];
    const float* g3 = (const float*)d_in[13];
    const float* b3 = (const float*)d_in[14];
    const float* m3 = (const float*)d_in[15];
    const float* v3 = (const float*)d_in[16];
    float* out = (float*)d_out;

    // ws: h1p [8*64*960] @0, h2p [8*64*960] @491520, h3 [8*64*784] @983040 (floats)
    float* h1p = (float*)d_ws;
    float* h2p = h1p + 491520;
    float* h3  = h2p + 491520;

    // zero h1p+h2p with our own fill (rocclr fillBuffer runs at 95 GB/s for small sizes)
    k0_zero<<<dim3(960), 256, 0, stream>>>((float4*)d_ws);

    k1_adder1x1<<<dim3(112, 4), 448, 0, stream>>>(x, w1, h1p);
    k2_peg_bn_relu<<<dim3(392), 256, 0, stream>>>(h1p, wp, g1, b1, m1, v1, h2p);
    k3_adder3x3_bn_relu<<<dim3(14, 4, 8), 448, 0, stream>>>(h2p, w2, g2, b2, m2, v2, h3);
    k6_adder1x1_bn_res_relu<<<dim3(112, 8), 448, 0, stream>>>(h3, w3, x, g3, b3, m3, v3, out);
}